// Round 1
// baseline (517.555 us; speedup 1.0000x reference)
//
#include <hip/hip_runtime.h>

using u16 = unsigned short;
using u32 = unsigned int;

typedef __attribute__((ext_vector_type(8))) short bf16x8;   // 8 bf16 (4 VGPRs) MFMA frag
typedef __attribute__((ext_vector_type(4))) float f32x4;
typedef __attribute__((ext_vector_type(8))) u16 u16x8;
typedef __attribute__((ext_vector_type(4))) u16 u16x4;

constexpr int NB = 64, NC = 729, NS = 243, ND = 512, ND2 = 1024;
constexpr int MS = NB * NS;   // 15552 set rows
constexpr int MC = NB * NC;   // 46656 cand rows

__device__ __forceinline__ u16 f2bf(float f) {
  u32 u = __builtin_bit_cast(u32, f);
  return (u16)((u + 0x7fffu + ((u >> 16) & 1u)) >> 16);   // RNE
}
__device__ __forceinline__ float bf2f(u16 h) {
  return __builtin_bit_cast(float, (u32)h << 16);
}
__device__ __forceinline__ void gload16(const void* g, void* l) {
  __builtin_amdgcn_global_load_lds((const __attribute__((address_space(1))) u32*)g,
                                   (__attribute__((address_space(3))) u32*)l, 16, 0, 0);
}

// ---------------- weight f32 -> bf16 cast ----------------
__global__ __launch_bounds__(256) void cast_bf16_k(const float* __restrict__ in,
                                                   u16* __restrict__ out, int n4) {
  int i = blockIdx.x * 256 + threadIdx.x;
  if (i >= n4) return;
  f32x4 v = ((const f32x4*)in)[i];
  u16x4 o;
  o.x = f2bf(v.x); o.y = f2bf(v.y); o.z = f2bf(v.z); o.w = f2bf(v.w);
  ((u16x4*)out)[i] = o;
}

// ---------------- CSR build (deterministic) ----------------
__global__ void build_csr_k(const int* __restrict__ idx, int* __restrict__ offs,
                            int* __restrict__ list) {
  __shared__ int cnts[NS];
  __shared__ int soffs[NS + 1];
  const int t = threadIdx.x;
  for (int s = t; s < NS; s += 256) cnts[s] = 0;
  __syncthreads();
  for (int e = t; e < 3 * NC; e += 256) atomicAdd(&cnts[idx[e]], 1);
  __syncthreads();
  if (t == 0) {
    int a = 0;
    for (int s = 0; s < NS; ++s) { soffs[s] = a; a += cnts[s]; }
    soffs[NS] = a;
  }
  __syncthreads();
  for (int s = t; s <= NS; s += 256) offs[s] = soffs[s];
  // deterministic fill: thread s scans all entries in order
  for (int s = t; s < NS; s += 256) {
    int p = soffs[s];
    for (int e = 0; e < 3 * NC; ++e)
      if (idx[e] == s) list[p++] = e / 3;   // candidate index (repeat(3) => c = e/3)
  }
}

// ---------------- per-set aggregation of cand_feat (pre-GEMM1 scatter) ----------------
__global__ __launch_bounds__(256) void agg_k(const float* __restrict__ cand_feat,
                                             const int* __restrict__ offs,
                                             const int* __restrict__ list,
                                             u16* __restrict__ agg) {
  int row = blockIdx.x * 4 + (threadIdx.x >> 6);
  if (row >= MS) return;
  int lane = threadIdx.x & 63;
  int b = row / NS, s = row - b * NS;
  int e0 = offs[s], e1 = offs[s + 1];
  const float* base = cand_feat + (size_t)b * NC * ND + lane * 8;
  f32x4 a0 = {0.f, 0.f, 0.f, 0.f}, a1 = {0.f, 0.f, 0.f, 0.f};
  for (int e = e0; e < e1; ++e) {
    const float* p = base + (size_t)list[e] * ND;
    a0 += *(const f32x4*)p;
    a1 += *(const f32x4*)(p + 4);
  }
  u16x8 o;
  o[0] = f2bf(a0.x); o[1] = f2bf(a0.y); o[2] = f2bf(a0.z); o[3] = f2bf(a0.w);
  o[4] = f2bf(a1.x); o[5] = f2bf(a1.y); o[6] = f2bf(a1.z); o[7] = f2bf(a1.w);
  *(u16x8*)(agg + (size_t)row * ND + lane * 8) = o;
}

// ---------------- 128x128 bf16 MFMA GEMM, C = A @ B^T  (both K-contiguous) ----------------
// EP=0: store f32 (no bias).  EP=1: bias + relu + store bf16.
template <int EP>
__global__ __launch_bounds__(256, 2) void gemm128_k(const u16* __restrict__ A,
                                                    const u16* __restrict__ Bw,
                                                    void* __restrict__ Out,
                                                    const float* __restrict__ bias,
                                                    int M, int N, int K) {
  constexpr int BK = 32;
  __shared__ u16 lA[128 * BK];
  __shared__ u16 lB[128 * BK];
  const int t = threadIdx.x;
  const int wid = t >> 6, lane = t & 63;
  const int MT = (M + 127) >> 7;
  const int mt = blockIdx.x % MT, nt = blockIdx.x / MT;
  const int m0 = mt << 7, n0 = nt << 7;
  const int kc = (t & 3) * 8;                // k element offset of this thread's 16B chunk
  int ra0 = m0 + (t >> 2);       if (ra0 > M - 1) ra0 = M - 1;   // clamp (tail tiles)
  int ra1 = m0 + 64 + (t >> 2);  if (ra1 > M - 1) ra1 = M - 1;
  const u16* gA0 = A + (size_t)ra0 * K + kc;
  const u16* gA1 = A + (size_t)ra1 * K + kc;
  const u16* gB0 = Bw + (size_t)(n0 + (t >> 2)) * K + kc;
  const u16* gB1 = Bw + (size_t)(n0 + 64 + (t >> 2)) * K + kc;
  u16* lA0 = lA + t * 8;        u16* lA1 = lA + 2048 + t * 8;
  u16* lB0 = lB + t * 8;        u16* lB1 = lB + 2048 + t * 8;

  f32x4 acc[4][4] = {};
  const int rowA = ((wid >> 1) << 6) + (lane & 15);
  const int rowB = ((wid & 1) << 6) + (lane & 15);
  const int kg = (lane >> 4) << 3;

  for (int kt = 0; kt < K; kt += BK) {
    gload16(gA0, lA0); gload16(gA1, lA1);
    gload16(gB0, lB0); gload16(gB1, lB1);
    gA0 += BK; gA1 += BK; gB0 += BK; gB1 += BK;
    __syncthreads();
    bf16x8 af[4], bfr[4];
#pragma unroll
    for (int i = 0; i < 4; ++i) {
      af[i]  = *(const bf16x8*)&lA[(rowA + i * 16) * BK + kg];
      bfr[i] = *(const bf16x8*)&lB[(rowB + i * 16) * BK + kg];
    }
#pragma unroll
    for (int mi = 0; mi < 4; ++mi)
#pragma unroll
      for (int ni = 0; ni < 4; ++ni)
        acc[mi][ni] = __builtin_amdgcn_mfma_f32_16x16x32_bf16(af[mi], bfr[ni], acc[mi][ni], 0, 0, 0);
    __syncthreads();
  }

  const int rb = m0 + ((wid >> 1) << 6) + ((lane >> 4) << 2);
  const int cb = n0 + ((wid & 1) << 6) + (lane & 15);
  if (EP == 0) {
    float* O = (float*)Out;
#pragma unroll
    for (int mi = 0; mi < 4; ++mi)
#pragma unroll
      for (int ni = 0; ni < 4; ++ni) {
        int cc = cb + ni * 16;
#pragma unroll
        for (int r = 0; r < 4; ++r) {
          int rr = rb + mi * 16 + r;
          if (rr < M) O[(size_t)rr * N + cc] = acc[mi][ni][r];
        }
      }
  } else {
    u16* O = (u16*)Out;
    float bv[4];
#pragma unroll
    for (int ni = 0; ni < 4; ++ni) bv[ni] = bias[cb + ni * 16];
#pragma unroll
    for (int mi = 0; mi < 4; ++mi)
#pragma unroll
      for (int ni = 0; ni < 4; ++ni) {
        int cc = cb + ni * 16;
#pragma unroll
        for (int r = 0; r < 4; ++r) {
          int rr = rb + mi * 16 + r;
          float v = fmaxf(acc[mi][ni][r] + bv[ni], 0.0f);
          if (rr < M) O[(size_t)rr * N + cc] = f2bf(v);
        }
      }
  }
}

// ---------------- set LN: set_out = LN(set_feat + (u1 + cnt*b_vc)/9) ----------------
__global__ __launch_bounds__(256) void set_ln_k(const float* __restrict__ u1,
                                                const float* __restrict__ set_feat,
                                                const int* __restrict__ offs,
                                                const float* __restrict__ b_vc,
                                                const float* __restrict__ gam,
                                                const float* __restrict__ bet,
                                                float* __restrict__ set_out,
                                                u16* __restrict__ set_out_bf) {
  int row = blockIdx.x * 4 + (threadIdx.x >> 6);
  if (row >= MS) return;
  int lane = threadIdx.x & 63;
  int s = row % NS;
  float c9 = (float)(offs[s + 1] - offs[s]) * (1.0f / 9.0f);
  size_t base = (size_t)row * ND + lane * 8;
  f32x4 u0 = *(const f32x4*)(u1 + base),       u1b = *(const f32x4*)(u1 + base + 4);
  f32x4 s0 = *(const f32x4*)(set_feat + base), s1  = *(const f32x4*)(set_feat + base + 4);
  f32x4 b0 = *(const f32x4*)(b_vc + lane * 8), b1  = *(const f32x4*)(b_vc + lane * 8 + 4);
  f32x4 x0 = s0 + u0 * (1.0f / 9.0f) + b0 * c9;
  f32x4 x1 = s1 + u1b * (1.0f / 9.0f) + b1 * c9;
  float sm = 0.f, sq = 0.f;
#pragma unroll
  for (int i = 0; i < 4; ++i) { sm += x0[i] + x1[i]; sq += x0[i] * x0[i] + x1[i] * x1[i]; }
#pragma unroll
  for (int m = 32; m; m >>= 1) { sm += __shfl_xor(sm, m); sq += __shfl_xor(sq, m); }
  float mu = sm * (1.0f / ND);
  float rs = rsqrtf(sq * (1.0f / ND) - mu * mu + 1e-5f);
  f32x4 g0 = *(const f32x4*)(gam + lane * 8), g1 = *(const f32x4*)(gam + lane * 8 + 4);
  f32x4 e0 = *(const f32x4*)(bet + lane * 8), e1 = *(const f32x4*)(bet + lane * 8 + 4);
  f32x4 y0, y1; u16x8 ob;
#pragma unroll
  for (int i = 0; i < 4; ++i) {
    y0[i] = (x0[i] - mu) * rs * g0[i] + e0[i];
    y1[i] = (x1[i] - mu) * rs * g1[i] + e1[i];
    ob[i] = f2bf(y0[i]); ob[i + 4] = f2bf(y1[i]);
  }
  *(f32x4*)(set_out + base) = y0;
  *(f32x4*)(set_out + base + 4) = y1;
  *(u16x8*)(set_out_bf + base) = ob;
}

// ---------------- cand LN: cand_h = LN(cand_feat + mean3(proj) + b_vs) ----------------
__global__ __launch_bounds__(256) void cand_ln_k(const float* __restrict__ cand_feat,
                                                 const float* __restrict__ proj,
                                                 const int* __restrict__ cidx,
                                                 const float* __restrict__ b_vs,
                                                 const float* __restrict__ gam,
                                                 const float* __restrict__ bet,
                                                 u16* __restrict__ cand_h) {
  int row = blockIdx.x * 4 + (threadIdx.x >> 6);
  if (row >= MC) return;
  int lane = threadIdx.x & 63;
  int b = row / NC, c = row - b * NC;
  int i0 = cidx[c * 3], i1 = cidx[c * 3 + 1], i2 = cidx[c * 3 + 2];
  const float* pb = proj + (size_t)b * NS * ND + lane * 8;
  f32x4 p00 = *(const f32x4*)(pb + (size_t)i0 * ND), p01 = *(const f32x4*)(pb + (size_t)i0 * ND + 4);
  f32x4 p10 = *(const f32x4*)(pb + (size_t)i1 * ND), p11 = *(const f32x4*)(pb + (size_t)i1 * ND + 4);
  f32x4 p20 = *(const f32x4*)(pb + (size_t)i2 * ND), p21 = *(const f32x4*)(pb + (size_t)i2 * ND + 4);
  size_t base = (size_t)row * ND + lane * 8;
  f32x4 c0 = *(const f32x4*)(cand_feat + base), c1 = *(const f32x4*)(cand_feat + base + 4);
  f32x4 v0 = *(const f32x4*)(b_vs + lane * 8),  v1 = *(const f32x4*)(b_vs + lane * 8 + 4);
  const float third = 1.0f / 3.0f;
  f32x4 x0 = c0 + (p00 + p10 + p20) * third + v0;
  f32x4 x1 = c1 + (p01 + p11 + p21) * third + v1;
  float sm = 0.f, sq = 0.f;
#pragma unroll
  for (int i = 0; i < 4; ++i) { sm += x0[i] + x1[i]; sq += x0[i] * x0[i] + x1[i] * x1[i]; }
#pragma unroll
  for (int m = 32; m; m >>= 1) { sm += __shfl_xor(sm, m); sq += __shfl_xor(sq, m); }
  float mu = sm * (1.0f / ND);
  float rs = rsqrtf(sq * (1.0f / ND) - mu * mu + 1e-5f);
  f32x4 g0 = *(const f32x4*)(gam + lane * 8), g1 = *(const f32x4*)(gam + lane * 8 + 4);
  f32x4 e0 = *(const f32x4*)(bet + lane * 8), e1 = *(const f32x4*)(bet + lane * 8 + 4);
  u16x8 ob;
#pragma unroll
  for (int i = 0; i < 4; ++i) {
    ob[i]     = f2bf((x0[i] - mu) * rs * g0[i] + e0[i]);
    ob[i + 4] = f2bf((x1[i] - mu) * rs * g1[i] + e1[i]);
  }
  *(u16x8*)(cand_h + base) = ob;
}

// ---------------- FF2 GEMM (K=1024) + bias + residual + LayerNorm, in-place over h1 ----------------
// BM=64 x BN=512 (full row per block -> LN fusable, in-place safe), 8 waves.
__global__ __launch_bounds__(512, 2) void gemm_ff2_ln_k(const u16* __restrict__ A,   // h1: M x 1024 bf16
                                                        const u16* __restrict__ Bw,  // W2: 512 x 1024 bf16
                                                        const u16* __restrict__ resid, // cand_h: M x 512 bf16
                                                        const float* __restrict__ bias,
                                                        const float* __restrict__ gam,
                                                        const float* __restrict__ bet,
                                                        float* __restrict__ Out,     // M x 512 f32 (same bytes as A rows)
                                                        int M) {
  constexpr int BK = 32, K = 1024, N = 512, BM = 64;
  __shared__ u16 lA[BM * BK];        // 4 KB
  __shared__ u16 lB[N * BK];         // 32 KB
  __shared__ float red[2][BM][8];    // 4 KB
  const int t = threadIdx.x, wid = t >> 6, lane = t & 63;
  const int m0 = blockIdx.x * BM;
  const int kc = (t & 3) * 8;
  const u16* gA0 = A + (size_t)(m0 + (t >> 2)) * K + kc;   // valid for t<256 (M % 64 == 0)
  const u16* gB[4]; u16* lBp[4];
#pragma unroll
  for (int i = 0; i < 4; ++i) {
    int ch = t + i * 512;
    gB[i]  = Bw + (size_t)(ch >> 2) * K + kc;
    lBp[i] = lB + ch * 8;
  }
  u16* lA0 = lA + t * 8;

  f32x4 acc[4][4] = {};
  const int rowA = lane & 15;                 // + mi*16
  const int rowB = (wid << 6) + (lane & 15);  // + ni*16
  const int kg = (lane >> 4) << 3;

  for (int kt = 0; kt < K; kt += BK) {
    if (t < 256) gload16(gA0, lA0);
#pragma unroll
    for (int i = 0; i < 4; ++i) gload16(gB[i], lBp[i]);
    gA0 += BK;
#pragma unroll
    for (int i = 0; i < 4; ++i) gB[i] += BK;
    __syncthreads();
    bf16x8 af[4], bfr[4];
#pragma unroll
    for (int i = 0; i < 4; ++i) {
      af[i]  = *(const bf16x8*)&lA[(rowA + i * 16) * BK + kg];
      bfr[i] = *(const bf16x8*)&lB[(rowB + i * 16) * BK + kg];
    }
#pragma unroll
    for (int mi = 0; mi < 4; ++mi)
#pragma unroll
      for (int ni = 0; ni < 4; ++ni)
        acc[mi][ni] = __builtin_amdgcn_mfma_f32_16x16x32_bf16(af[mi], bfr[ni], acc[mi][ni], 0, 0, 0);
    __syncthreads();
  }

  const int g = lane >> 4, li = lane & 15;
  float bv[4], gv[4], ev[4];
#pragma unroll
  for (int ni = 0; ni < 4; ++ni) {
    int col = (wid << 6) + ni * 16 + li;
    bv[ni] = bias[col]; gv[ni] = gam[col]; ev[ni] = bet[col];
  }
  // value = acc + bias + residual ; per-row partial sums -> LDS
#pragma unroll
  for (int mi = 0; mi < 4; ++mi)
#pragma unroll
    for (int r = 0; r < 4; ++r) {
      int rl = mi * 16 + g * 4 + r;
      size_t rg = (size_t)(m0 + rl);
      float s = 0.f, q = 0.f;
#pragma unroll
      for (int ni = 0; ni < 4; ++ni) {
        int col = (wid << 6) + ni * 16 + li;
        float v = acc[mi][ni][r] + bv[ni] + bf2f(resid[rg * 512 + col]);
        acc[mi][ni][r] = v;
        s += v; q += v * v;
      }
#pragma unroll
      for (int m = 8; m; m >>= 1) { s += __shfl_xor(s, m); q += __shfl_xor(q, m); }
      if (li == 0) { red[0][rl][wid] = s; red[1][rl][wid] = q; }
    }
  __syncthreads();
#pragma unroll
  for (int mi = 0; mi < 4; ++mi)
#pragma unroll
    for (int r = 0; r < 4; ++r) {
      int rl = mi * 16 + g * 4 + r;
      float s = 0.f, q = 0.f;
#pragma unroll
      for (int w = 0; w < 8; ++w) { s += red[0][rl][w]; q += red[1][rl][w]; }
      float mu = s * (1.0f / 512.0f);
      float rs = rsqrtf(q * (1.0f / 512.0f) - mu * mu + 1e-5f);
      size_t rg = (size_t)(m0 + rl);
#pragma unroll
      for (int ni = 0; ni < 4; ++ni) {
        int col = (wid << 6) + ni * 16 + li;
        Out[rg * 512 + col] = (acc[mi][ni][r] - mu) * rs * gv[ni] + ev[ni];
      }
    }
}

// ---------------- launcher ----------------
extern "C" void kernel_launch(void* const* d_in, const int* in_sizes, int n_in,
                              void* d_out, int out_size, void* d_ws, size_t ws_size,
                              hipStream_t stream) {
  const float* cand_feat = (const float*)d_in[0];
  const float* set_feat  = (const float*)d_in[1];
  const float* W_vc  = (const float*)d_in[2];
  const float* b_vc  = (const float*)d_in[3];
  const float* W_vs  = (const float*)d_in[4];
  const float* b_vs  = (const float*)d_in[5];
  const float* ff_W1 = (const float*)d_in[6];
  const float* ff_b1 = (const float*)d_in[7];
  const float* ff_W2 = (const float*)d_in[8];
  const float* ff_b2 = (const float*)d_in[9];
  const float* g_set  = (const float*)d_in[10];
  const float* be_set = (const float*)d_in[11];
  const float* g_cand = (const float*)d_in[12];
  const float* be_cand= (const float*)d_in[13];
  const float* g_ff   = (const float*)d_in[14];
  const float* be_ff  = (const float*)d_in[15];
  const int*   cidx   = (const int*)d_in[16];
  (void)in_sizes; (void)n_in; (void)out_size; (void)ws_size;
  (void)be_cand; (void)g_cand; // used below; silence if optimized differently

  // workspace layout (~66 MiB)
  char* ws = (char*)d_ws;
  u16* w_vc_b = (u16*)(ws + 0);
  u16* w_vs_b = (u16*)(ws + (512 << 10));
  u16* w1_b   = (u16*)(ws + (1 << 20));
  u16* w2_b   = (u16*)(ws + (2 << 20));
  int* offs   = (int*)(ws + (3 << 20));
  int* list   = (int*)(ws + (3 << 20) + 4096);
  u16* setb   = (u16*)(ws + (4 << 20));        // 15.9 MB  set_out bf16
  u16* candh  = (u16*)(ws + (20 << 20));       // 45.6 MB  cand_h bf16

  // d_out region reuse (cand region = 95.55 MB, written last by FF2 kernel):
  float* out_cand = (float*)d_out;
  float* out_set  = out_cand + (size_t)MC * ND;
  u16*   agg  = (u16*)out_set;     // 15.9 MB, dead before set_out written
  float* u1   = out_cand;          // GEMM1 out, dead after set_ln
  float* proj = out_cand;          // GEMM2 out, dead after cand_ln
  u16*   h1   = (u16*)out_cand;    // FF1 out (46656 x 1024 bf16 = exactly the cand region)

  cast_bf16_k<<<(ND * ND / 4 + 255) / 256, 256, 0, stream>>>(W_vc, w_vc_b, ND * ND / 4);
  cast_bf16_k<<<(ND * ND / 4 + 255) / 256, 256, 0, stream>>>(W_vs, w_vs_b, ND * ND / 4);
  cast_bf16_k<<<(ND2 * ND / 4 + 255) / 256, 256, 0, stream>>>(ff_W1, w1_b, ND2 * ND / 4);
  cast_bf16_k<<<(ND * ND2 / 4 + 255) / 256, 256, 0, stream>>>(ff_W2, w2_b, ND * ND2 / 4);
  build_csr_k<<<1, 256, 0, stream>>>(cidx, offs, list);
  agg_k<<<(MS + 3) / 4, 256, 0, stream>>>(cand_feat, offs, list, agg);
  gemm128_k<0><<<122 * 4, 256, 0, stream>>>(agg, w_vc_b, u1, nullptr, MS, ND, ND);
  set_ln_k<<<(MS + 3) / 4, 256, 0, stream>>>(u1, set_feat, offs, b_vc, g_set, be_set, out_set, setb);
  gemm128_k<0><<<122 * 4, 256, 0, stream>>>(setb, w_vs_b, proj, nullptr, MS, ND, ND);
  cand_ln_k<<<(MC + 3) / 4, 256, 0, stream>>>(cand_feat, proj, cidx, b_vs, g_cand, be_cand, candh);
  gemm128_k<1><<<365 * 8, 256, 0, stream>>>(candh, w1_b, h1, ff_b1, MC, ND2, ND);
  gemm_ff2_ln_k<<<729, 512, 0, stream>>>(h1, w2_b, candh, ff_b2, g_ff, be_ff, out_cand, MC);
}

// Round 2
// 514.337 us; speedup vs baseline: 1.0063x; 1.0063x over previous
//
#include <hip/hip_runtime.h>

using u16 = unsigned short;
using u32 = unsigned int;

typedef __attribute__((ext_vector_type(8))) short bf16x8;   // 8 bf16 (4 VGPRs) MFMA frag
typedef __attribute__((ext_vector_type(4))) float f32x4;
typedef __attribute__((ext_vector_type(8))) u16 u16x8;
typedef __attribute__((ext_vector_type(4))) u16 u16x4;

constexpr int NB = 64, NC = 729, NS = 243, ND = 512, ND2 = 1024;
constexpr int MS = NB * NS;   // 15552 set rows
constexpr int MC = NB * NC;   // 46656 cand rows

__device__ __forceinline__ u16 f2bf(float f) {
  u32 u = __builtin_bit_cast(u32, f);
  return (u16)((u + 0x7fffu + ((u >> 16) & 1u)) >> 16);   // RNE
}
__device__ __forceinline__ float bf2f(u16 h) {
  return __builtin_bit_cast(float, (u32)h << 16);
}
__device__ __forceinline__ void gload16(const void* g, void* l) {
  __builtin_amdgcn_global_load_lds((const __attribute__((address_space(1))) u32*)g,
                                   (__attribute__((address_space(3))) u32*)l, 16, 0, 0);
}

// ---------------- weight f32 -> bf16 cast ----------------
__global__ __launch_bounds__(256) void cast_bf16_k(const float* __restrict__ in,
                                                   u16* __restrict__ out, int n4) {
  int i = blockIdx.x * 256 + threadIdx.x;
  if (i >= n4) return;
  f32x4 v = ((const f32x4*)in)[i];
  u16x4 o;
  o.x = f2bf(v.x); o.y = f2bf(v.y); o.z = f2bf(v.z); o.w = f2bf(v.w);
  ((u16x4*)out)[i] = o;
}

// ---------------- CSR build (deterministic) ----------------
__global__ void build_csr_k(const int* __restrict__ idx, int* __restrict__ offs,
                            int* __restrict__ list) {
  __shared__ int cnts[NS];
  __shared__ int soffs[NS + 1];
  const int t = threadIdx.x;
  for (int s = t; s < NS; s += 256) cnts[s] = 0;
  __syncthreads();
  for (int e = t; e < 3 * NC; e += 256) atomicAdd(&cnts[idx[e]], 1);
  __syncthreads();
  if (t == 0) {
    int a = 0;
    for (int s = 0; s < NS; ++s) { soffs[s] = a; a += cnts[s]; }
    soffs[NS] = a;
  }
  __syncthreads();
  for (int s = t; s <= NS; s += 256) offs[s] = soffs[s];
  // deterministic fill: thread s scans all entries in order
  for (int s = t; s < NS; s += 256) {
    int p = soffs[s];
    for (int e = 0; e < 3 * NC; ++e)
      if (idx[e] == s) list[p++] = e / 3;   // candidate index (repeat(3) => c = e/3)
  }
}

// ---------------- per-set aggregation of cand_feat (pre-GEMM1 scatter) ----------------
__global__ __launch_bounds__(256) void agg_k(const float* __restrict__ cand_feat,
                                             const int* __restrict__ offs,
                                             const int* __restrict__ list,
                                             u16* __restrict__ agg) {
  int row = blockIdx.x * 4 + (threadIdx.x >> 6);
  if (row >= MS) return;
  int lane = threadIdx.x & 63;
  int b = row / NS, s = row - b * NS;
  int e0 = offs[s], e1 = offs[s + 1];
  const float* base = cand_feat + (size_t)b * NC * ND + lane * 8;
  f32x4 a0 = {0.f, 0.f, 0.f, 0.f}, a1 = {0.f, 0.f, 0.f, 0.f};
  for (int e = e0; e < e1; ++e) {
    const float* p = base + (size_t)list[e] * ND;
    a0 += *(const f32x4*)p;
    a1 += *(const f32x4*)(p + 4);
  }
  u16x8 o;
  o[0] = f2bf(a0.x); o[1] = f2bf(a0.y); o[2] = f2bf(a0.z); o[3] = f2bf(a0.w);
  o[4] = f2bf(a1.x); o[5] = f2bf(a1.y); o[6] = f2bf(a1.z); o[7] = f2bf(a1.w);
  *(u16x8*)(agg + (size_t)row * ND + lane * 8) = o;
}

// ---------------- 128x128 bf16 MFMA GEMM, C = A @ B^T  (both K-contiguous) ----------------
// EP=0: store f32 (no bias).  EP=1: bias + relu + store bf16.
template <int EP>
__global__ __launch_bounds__(256, 2) void gemm128_k(const u16* __restrict__ A,
                                                    const u16* __restrict__ Bw,
                                                    void* __restrict__ Out,
                                                    const float* __restrict__ bias,
                                                    int M, int N, int K) {
  constexpr int BK = 32;
  __shared__ u16 lA[128 * BK];
  __shared__ u16 lB[128 * BK];
  const int t = threadIdx.x;
  const int wid = t >> 6, lane = t & 63;
  const int MT = (M + 127) >> 7;
  const int mt = blockIdx.x % MT, nt = blockIdx.x / MT;
  const int m0 = mt << 7, n0 = nt << 7;
  const int kc = (t & 3) * 8;                // k element offset of this thread's 16B chunk
  int ra0 = m0 + (t >> 2);       if (ra0 > M - 1) ra0 = M - 1;   // clamp (tail tiles)
  int ra1 = m0 + 64 + (t >> 2);  if (ra1 > M - 1) ra1 = M - 1;
  const u16* gA0 = A + (size_t)ra0 * K + kc;
  const u16* gA1 = A + (size_t)ra1 * K + kc;
  const u16* gB0 = Bw + (size_t)(n0 + (t >> 2)) * K + kc;
  const u16* gB1 = Bw + (size_t)(n0 + 64 + (t >> 2)) * K + kc;
  u16* lA0 = lA + t * 8;        u16* lA1 = lA + 2048 + t * 8;
  u16* lB0 = lB + t * 8;        u16* lB1 = lB + 2048 + t * 8;

  f32x4 acc[4][4] = {};
  const int rowA = ((wid >> 1) << 6) + (lane & 15);
  const int rowB = ((wid & 1) << 6) + (lane & 15);
  const int kg = (lane >> 4) << 3;

  for (int kt = 0; kt < K; kt += BK) {
    gload16(gA0, lA0); gload16(gA1, lA1);
    gload16(gB0, lB0); gload16(gB1, lB1);
    gA0 += BK; gA1 += BK; gB0 += BK; gB1 += BK;
    __syncthreads();
    bf16x8 af[4], bfr[4];
#pragma unroll
    for (int i = 0; i < 4; ++i) {
      af[i]  = *(const bf16x8*)&lA[(rowA + i * 16) * BK + kg];
      bfr[i] = *(const bf16x8*)&lB[(rowB + i * 16) * BK + kg];
    }
#pragma unroll
    for (int mi = 0; mi < 4; ++mi)
#pragma unroll
      for (int ni = 0; ni < 4; ++ni)
        acc[mi][ni] = __builtin_amdgcn_mfma_f32_16x16x32_bf16(af[mi], bfr[ni], acc[mi][ni], 0, 0, 0);
    __syncthreads();
  }

  const int rb = m0 + ((wid >> 1) << 6) + ((lane >> 4) << 2);
  const int cb = n0 + ((wid & 1) << 6) + (lane & 15);
  if (EP == 0) {
    float* O = (float*)Out;
#pragma unroll
    for (int mi = 0; mi < 4; ++mi)
#pragma unroll
      for (int ni = 0; ni < 4; ++ni) {
        int cc = cb + ni * 16;
#pragma unroll
        for (int r = 0; r < 4; ++r) {
          int rr = rb + mi * 16 + r;
          if (rr < M) O[(size_t)rr * N + cc] = acc[mi][ni][r];
        }
      }
  } else {
    u16* O = (u16*)Out;
    float bv[4];
#pragma unroll
    for (int ni = 0; ni < 4; ++ni) bv[ni] = bias[cb + ni * 16];
#pragma unroll
    for (int mi = 0; mi < 4; ++mi)
#pragma unroll
      for (int ni = 0; ni < 4; ++ni) {
        int cc = cb + ni * 16;
#pragma unroll
        for (int r = 0; r < 4; ++r) {
          int rr = rb + mi * 16 + r;
          float v = fmaxf(acc[mi][ni][r] + bv[ni], 0.0f);
          if (rr < M) O[(size_t)rr * N + cc] = f2bf(v);
        }
      }
  }
}

// ---------------- set LN: set_out = LN(set_feat + (u1 + cnt*b_vc)/9) ----------------
__global__ __launch_bounds__(256) void set_ln_k(const float* __restrict__ u1,
                                                const float* __restrict__ set_feat,
                                                const int* __restrict__ offs,
                                                const float* __restrict__ b_vc,
                                                const float* __restrict__ gam,
                                                const float* __restrict__ bet,
                                                float* __restrict__ set_out,
                                                u16* __restrict__ set_out_bf) {
  int row = blockIdx.x * 4 + (threadIdx.x >> 6);
  if (row >= MS) return;
  int lane = threadIdx.x & 63;
  int s = row % NS;
  float c9 = (float)(offs[s + 1] - offs[s]) * (1.0f / 9.0f);
  size_t base = (size_t)row * ND + lane * 8;
  f32x4 u0 = *(const f32x4*)(u1 + base),       u1b = *(const f32x4*)(u1 + base + 4);
  f32x4 s0 = *(const f32x4*)(set_feat + base), s1  = *(const f32x4*)(set_feat + base + 4);
  f32x4 b0 = *(const f32x4*)(b_vc + lane * 8), b1  = *(const f32x4*)(b_vc + lane * 8 + 4);
  f32x4 x0 = s0 + u0 * (1.0f / 9.0f) + b0 * c9;
  f32x4 x1 = s1 + u1b * (1.0f / 9.0f) + b1 * c9;
  float sm = 0.f, sq = 0.f;
#pragma unroll
  for (int i = 0; i < 4; ++i) { sm += x0[i] + x1[i]; sq += x0[i] * x0[i] + x1[i] * x1[i]; }
#pragma unroll
  for (int m = 32; m; m >>= 1) { sm += __shfl_xor(sm, m); sq += __shfl_xor(sq, m); }
  float mu = sm * (1.0f / ND);
  float rs = rsqrtf(sq * (1.0f / ND) - mu * mu + 1e-5f);
  f32x4 g0 = *(const f32x4*)(gam + lane * 8), g1 = *(const f32x4*)(gam + lane * 8 + 4);
  f32x4 e0 = *(const f32x4*)(bet + lane * 8), e1 = *(const f32x4*)(bet + lane * 8 + 4);
  f32x4 y0, y1; u16x8 ob;
#pragma unroll
  for (int i = 0; i < 4; ++i) {
    y0[i] = (x0[i] - mu) * rs * g0[i] + e0[i];
    y1[i] = (x1[i] - mu) * rs * g1[i] + e1[i];
    ob[i] = f2bf(y0[i]); ob[i + 4] = f2bf(y1[i]);
  }
  *(f32x4*)(set_out + base) = y0;
  *(f32x4*)(set_out + base + 4) = y1;
  *(u16x8*)(set_out_bf + base) = ob;
}

// ---------------- cand LN: cand_h = LN(cand_feat + mean3(proj) + b_vs) ----------------
__global__ __launch_bounds__(256) void cand_ln_k(const float* __restrict__ cand_feat,
                                                 const float* __restrict__ proj,
                                                 const int* __restrict__ cidx,
                                                 const float* __restrict__ b_vs,
                                                 const float* __restrict__ gam,
                                                 const float* __restrict__ bet,
                                                 u16* __restrict__ cand_h) {
  int row = blockIdx.x * 4 + (threadIdx.x >> 6);
  if (row >= MC) return;
  int lane = threadIdx.x & 63;
  int b = row / NC, c = row - b * NC;
  int i0 = cidx[c * 3], i1 = cidx[c * 3 + 1], i2 = cidx[c * 3 + 2];
  const float* pb = proj + (size_t)b * NS * ND + lane * 8;
  f32x4 p00 = *(const f32x4*)(pb + (size_t)i0 * ND), p01 = *(const f32x4*)(pb + (size_t)i0 * ND + 4);
  f32x4 p10 = *(const f32x4*)(pb + (size_t)i1 * ND), p11 = *(const f32x4*)(pb + (size_t)i1 * ND + 4);
  f32x4 p20 = *(const f32x4*)(pb + (size_t)i2 * ND), p21 = *(const f32x4*)(pb + (size_t)i2 * ND + 4);
  size_t base = (size_t)row * ND + lane * 8;
  f32x4 c0 = *(const f32x4*)(cand_feat + base), c1 = *(const f32x4*)(cand_feat + base + 4);
  f32x4 v0 = *(const f32x4*)(b_vs + lane * 8),  v1 = *(const f32x4*)(b_vs + lane * 8 + 4);
  const float third = 1.0f / 3.0f;
  f32x4 x0 = c0 + (p00 + p10 + p20) * third + v0;
  f32x4 x1 = c1 + (p01 + p11 + p21) * third + v1;
  float sm = 0.f, sq = 0.f;
#pragma unroll
  for (int i = 0; i < 4; ++i) { sm += x0[i] + x1[i]; sq += x0[i] * x0[i] + x1[i] * x1[i]; }
#pragma unroll
  for (int m = 32; m; m >>= 1) { sm += __shfl_xor(sm, m); sq += __shfl_xor(sq, m); }
  float mu = sm * (1.0f / ND);
  float rs = rsqrtf(sq * (1.0f / ND) - mu * mu + 1e-5f);
  f32x4 g0 = *(const f32x4*)(gam + lane * 8), g1 = *(const f32x4*)(gam + lane * 8 + 4);
  f32x4 e0 = *(const f32x4*)(bet + lane * 8), e1 = *(const f32x4*)(bet + lane * 8 + 4);
  u16x8 ob;
#pragma unroll
  for (int i = 0; i < 4; ++i) {
    ob[i]     = f2bf((x0[i] - mu) * rs * g0[i] + e0[i]);
    ob[i + 4] = f2bf((x1[i] - mu) * rs * g1[i] + e1[i]);
  }
  *(u16x8*)(cand_h + base) = ob;
}

// ---------------- FF2 GEMM (K=1024) + bias + residual + LayerNorm, in-place over h1 ----------------
// BM=64 x BN=512 (full row per block -> LN fusable, in-place safe), BK=64, 8 waves.
// k-major LDS layout (wave w loads k-chunk w, lane l loads row l) => linear global_load_lds
// dest AND conflict-free ds_read_b128 (16B row stride). M % 64 == 0 (no tail).
__global__ __launch_bounds__(512, 4) void gemm_ff2_ln_k(const u16* __restrict__ A,   // h1: M x 1024 bf16
                                                        const u16* __restrict__ Bw,  // W2: 512 x 1024 bf16
                                                        const u16* __restrict__ resid, // cand_h: M x 512 bf16
                                                        const float* __restrict__ bias,
                                                        const float* __restrict__ gam,
                                                        const float* __restrict__ bet,
                                                        float* __restrict__ Out,     // M x 512 f32 (same bytes as A rows)
                                                        int M) {
  constexpr int BK = 64, K = 1024, N = 512, BM = 64;
  __shared__ u16 lA[BM * BK];        //  8 KB, layout [kc(8)][row(64)][8]
  __shared__ u16 lB[N * BK];         // 64 KB, layout [kc(8)][row(512)][8]
  __shared__ float red[2][BM][8];    //  4 KB
  const int t = threadIdx.x, wid = t >> 6, lane = t & 63;
  const int m0 = blockIdx.x * BM;

  // staging pointers: wave wid owns k-chunk wid (8 bf16 = 16B), lane owns row
  const u16* gA  = A  + (size_t)(m0 + lane) * K + wid * 8;   // advance by BK per step
  const u16* gBb = Bw + (size_t)lane * K + wid * 8;          // + i*64*K per sub-iter
  u16* lAd  = lA + t * 8;                                    // = wid*512 + lane*8
  u16* lBd  = lB + wid * 4096 + lane * 8;                    // + i*512 per sub-iter

  // fragment read bases (all further addressing via compile-time immediates)
  const u16* aA = lA + (lane >> 4) * 512  + (lane & 15) * 8;
  const u16* bB = lB + (lane >> 4) * 4096 + (wid * 64 + (lane & 15)) * 8;

  f32x4 acc[4][4] = {};

  for (int kt = 0; kt < K; kt += BK) {
    gload16(gA, lAd);
#pragma unroll
    for (int i = 0; i < 8; ++i) gload16(gBb + (size_t)i * 64 * K, lBd + i * 512);
    gA += BK; gBb += BK;
    __syncthreads();
#pragma unroll
    for (int kk = 0; kk < BK; kk += 32) {
      bf16x8 af[4], bfr[4];
#pragma unroll
      for (int i = 0; i < 4; ++i) {
        af[i]  = *(const bf16x8*)(aA + kk * 64  + i * 128);
        bfr[i] = *(const bf16x8*)(bB + kk * 512 + i * 128);
      }
#pragma unroll
      for (int mi = 0; mi < 4; ++mi)
#pragma unroll
        for (int ni = 0; ni < 4; ++ni)
          acc[mi][ni] = __builtin_amdgcn_mfma_f32_16x16x32_bf16(af[mi], bfr[ni], acc[mi][ni], 0, 0, 0);
    }
    __syncthreads();
  }

  const int g = lane >> 4, li = lane & 15;
  float bv[4], gv[4], ev[4];
#pragma unroll
  for (int ni = 0; ni < 4; ++ni) {
    int col = (wid << 6) + ni * 16 + li;
    bv[ni] = bias[col]; gv[ni] = gam[col]; ev[ni] = bet[col];
  }
  // value = acc + bias + residual ; per-row partial sums -> LDS
#pragma unroll
  for (int mi = 0; mi < 4; ++mi)
#pragma unroll
    for (int r = 0; r < 4; ++r) {
      int rl = mi * 16 + g * 4 + r;
      size_t rg = (size_t)(m0 + rl);
      float s = 0.f, q = 0.f;
#pragma unroll
      for (int ni = 0; ni < 4; ++ni) {
        int col = (wid << 6) + ni * 16 + li;
        float v = acc[mi][ni][r] + bv[ni] + bf2f(resid[rg * 512 + col]);
        acc[mi][ni][r] = v;
        s += v; q += v * v;
      }
#pragma unroll
      for (int m = 8; m; m >>= 1) { s += __shfl_xor(s, m); q += __shfl_xor(q, m); }
      if (li == 0) { red[0][rl][wid] = s; red[1][rl][wid] = q; }
    }
  __syncthreads();
#pragma unroll
  for (int mi = 0; mi < 4; ++mi)
#pragma unroll
    for (int r = 0; r < 4; ++r) {
      int rl = mi * 16 + g * 4 + r;
      float s = 0.f, q = 0.f;
#pragma unroll
      for (int w = 0; w < 8; ++w) { s += red[0][rl][w]; q += red[1][rl][w]; }
      float mu = s * (1.0f / 512.0f);
      float rs = rsqrtf(q * (1.0f / 512.0f) - mu * mu + 1e-5f);
      size_t rg = (size_t)(m0 + rl);
#pragma unroll
      for (int ni = 0; ni < 4; ++ni) {
        int col = (wid << 6) + ni * 16 + li;
        Out[rg * 512 + col] = (acc[mi][ni][r] - mu) * rs * gv[ni] + ev[ni];
      }
    }
}

// ---------------- launcher ----------------
extern "C" void kernel_launch(void* const* d_in, const int* in_sizes, int n_in,
                              void* d_out, int out_size, void* d_ws, size_t ws_size,
                              hipStream_t stream) {
  const float* cand_feat = (const float*)d_in[0];
  const float* set_feat  = (const float*)d_in[1];
  const float* W_vc  = (const float*)d_in[2];
  const float* b_vc  = (const float*)d_in[3];
  const float* W_vs  = (const float*)d_in[4];
  const float* b_vs  = (const float*)d_in[5];
  const float* ff_W1 = (const float*)d_in[6];
  const float* ff_b1 = (const float*)d_in[7];
  const float* ff_W2 = (const float*)d_in[8];
  const float* ff_b2 = (const float*)d_in[9];
  const float* g_set  = (const float*)d_in[10];
  const float* be_set = (const float*)d_in[11];
  const float* g_cand = (const float*)d_in[12];
  const float* be_cand= (const float*)d_in[13];
  const float* g_ff   = (const float*)d_in[14];
  const float* be_ff  = (const float*)d_in[15];
  const int*   cidx   = (const int*)d_in[16];
  (void)in_sizes; (void)n_in; (void)out_size; (void)ws_size;

  // workspace layout (~66 MiB)
  char* ws = (char*)d_ws;
  u16* w_vc_b = (u16*)(ws + 0);
  u16* w_vs_b = (u16*)(ws + (512 << 10));
  u16* w1_b   = (u16*)(ws + (1 << 20));
  u16* w2_b   = (u16*)(ws + (2 << 20));
  int* offs   = (int*)(ws + (3 << 20));
  int* list   = (int*)(ws + (3 << 20) + 4096);
  u16* setb   = (u16*)(ws + (4 << 20));        // 15.9 MB  set_out bf16
  u16* candh  = (u16*)(ws + (20 << 20));       // 45.6 MB  cand_h bf16

  // d_out region reuse (cand region = 95.55 MB, written last by FF2 kernel):
  float* out_cand = (float*)d_out;
  float* out_set  = out_cand + (size_t)MC * ND;
  u16*   agg  = (u16*)out_set;     // 15.9 MB, dead before set_out written
  float* u1   = out_cand;          // GEMM1 out, dead after set_ln
  float* proj = out_cand;          // GEMM2 out, dead after cand_ln
  u16*   h1   = (u16*)out_cand;    // FF1 out (46656 x 1024 bf16 = exactly the cand region)

  cast_bf16_k<<<(ND * ND / 4 + 255) / 256, 256, 0, stream>>>(W_vc, w_vc_b, ND * ND / 4);
  cast_bf16_k<<<(ND * ND / 4 + 255) / 256, 256, 0, stream>>>(W_vs, w_vs_b, ND * ND / 4);
  cast_bf16_k<<<(ND2 * ND / 4 + 255) / 256, 256, 0, stream>>>(ff_W1, w1_b, ND2 * ND / 4);
  cast_bf16_k<<<(ND * ND2 / 4 + 255) / 256, 256, 0, stream>>>(ff_W2, w2_b, ND * ND2 / 4);
  build_csr_k<<<1, 256, 0, stream>>>(cidx, offs, list);
  agg_k<<<(MS + 3) / 4, 256, 0, stream>>>(cand_feat, offs, list, agg);
  gemm128_k<0><<<122 * 4, 256, 0, stream>>>(agg, w_vc_b, u1, nullptr, MS, ND, ND);
  set_ln_k<<<(MS + 3) / 4, 256, 0, stream>>>(u1, set_feat, offs, b_vc, g_set, be_set, out_set, setb);
  gemm128_k<0><<<122 * 4, 256, 0, stream>>>(setb, w_vs_b, proj, nullptr, MS, ND, ND);
  cand_ln_k<<<(MC + 3) / 4, 256, 0, stream>>>(cand_feat, proj, cidx, b_vs, g_cand, be_cand, candh);
  gemm128_k<1><<<365 * 8, 256, 0, stream>>>(candh, w1_b, h1, ff_b1, MC, ND2, ND);
  gemm_ff2_ln_k<<<729, 512, 0, stream>>>(h1, w2_b, candh, ff_b2, g_ff, be_ff, out_cand, MC);
}

// Round 3
// 467.920 us; speedup vs baseline: 1.1061x; 1.0992x over previous
//
#include <hip/hip_runtime.h>

using u16 = unsigned short;
using u32 = unsigned int;

typedef __attribute__((ext_vector_type(8))) short bf16x8;   // 8 bf16 (4 VGPRs) MFMA frag
typedef __attribute__((ext_vector_type(4))) float f32x4;
typedef __attribute__((ext_vector_type(8))) u16 u16x8;
typedef __attribute__((ext_vector_type(4))) u16 u16x4;

constexpr int NB = 64, NC = 729, NS = 243, ND = 512, ND2 = 1024;
constexpr int MS = NB * NS;   // 15552 set rows
constexpr int MC = NB * NC;   // 46656 cand rows

__device__ __forceinline__ u16 f2bf(float f) {
  u32 u = __builtin_bit_cast(u32, f);
  return (u16)((u + 0x7fffu + ((u >> 16) & 1u)) >> 16);   // RNE
}
__device__ __forceinline__ float bf2f(u16 h) {
  return __builtin_bit_cast(float, (u32)h << 16);
}
__device__ __forceinline__ void gload16(const void* g, void* l) {
  __builtin_amdgcn_global_load_lds((const __attribute__((address_space(1))) u32*)g,
                                   (__attribute__((address_space(3))) u32*)l, 16, 0, 0);
}

// ---------------- weight f32 -> bf16 cast ----------------
__global__ __launch_bounds__(256) void cast_bf16_k(const float* __restrict__ in,
                                                   u16* __restrict__ out, int n4) {
  int i = blockIdx.x * 256 + threadIdx.x;
  if (i >= n4) return;
  f32x4 v = ((const f32x4*)in)[i];
  u16x4 o;
  o.x = f2bf(v.x); o.y = f2bf(v.y); o.z = f2bf(v.z); o.w = f2bf(v.w);
  ((u16x4*)out)[i] = o;
}

// ---------------- CSR build (deterministic) ----------------
__global__ void build_csr_k(const int* __restrict__ idx, int* __restrict__ offs,
                            int* __restrict__ list) {
  __shared__ int cnts[NS];
  __shared__ int soffs[NS + 1];
  const int t = threadIdx.x;
  for (int s = t; s < NS; s += 256) cnts[s] = 0;
  __syncthreads();
  for (int e = t; e < 3 * NC; e += 256) atomicAdd(&cnts[idx[e]], 1);
  __syncthreads();
  if (t == 0) {
    int a = 0;
    for (int s = 0; s < NS; ++s) { soffs[s] = a; a += cnts[s]; }
    soffs[NS] = a;
  }
  __syncthreads();
  for (int s = t; s <= NS; s += 256) offs[s] = soffs[s];
  for (int s = t; s < NS; s += 256) {
    int p = soffs[s];
    for (int e = 0; e < 3 * NC; ++e)
      if (idx[e] == s) list[p++] = e / 3;   // candidate index (repeat(3) => c = e/3)
  }
}

// ---------------- per-set aggregation of cand_feat (pre-GEMM1 scatter) ----------------
__global__ __launch_bounds__(256) void agg_k(const float* __restrict__ cand_feat,
                                             const int* __restrict__ offs,
                                             const int* __restrict__ list,
                                             u16* __restrict__ agg) {
  int row = blockIdx.x * 4 + (threadIdx.x >> 6);
  if (row >= MS) return;
  int lane = threadIdx.x & 63;
  int b = row / NS, s = row - b * NS;
  int e0 = offs[s], e1 = offs[s + 1];
  const float* base = cand_feat + (size_t)b * NC * ND + lane * 8;
  f32x4 a0 = {0.f, 0.f, 0.f, 0.f}, a1 = {0.f, 0.f, 0.f, 0.f};
  for (int e = e0; e < e1; ++e) {
    const float* p = base + (size_t)list[e] * ND;
    a0 += *(const f32x4*)p;
    a1 += *(const f32x4*)(p + 4);
  }
  u16x8 o;
  o[0] = f2bf(a0.x); o[1] = f2bf(a0.y); o[2] = f2bf(a0.z); o[3] = f2bf(a0.w);
  o[4] = f2bf(a1.x); o[5] = f2bf(a1.y); o[6] = f2bf(a1.z); o[7] = f2bf(a1.w);
  *(u16x8*)(agg + (size_t)row * ND + lane * 8) = o;
}

// ============ 128x128 bf16 MFMA GEMM v3, C = A @ B^T ============
// Coalesced staging (8 lanes/row, 128B = 1 line per row-chunk), XOR-swizzled LDS
// (pre-swizzled global source, linear LDS dest), double-buffered with
// STAGE(next) || COMPUTE(cur) so vmcnt(0) drain lands after the MFMA cluster.
// EP=0: store f32 (no bias).  EP=1: bias + relu + store bf16.
template <int EP>
__global__ __launch_bounds__(256, 2) void gemm_v3_k(const u16* __restrict__ A,
                                                    const u16* __restrict__ Bw,
                                                    void* __restrict__ Out,
                                                    const float* __restrict__ bias,
                                                    int M, int N, int K) {
  constexpr int BK = 64;
  __shared__ u16 lA0[128 * BK], lA1[128 * BK];   // 16 KB each pair
  __shared__ u16 lB0[128 * BK], lB1[128 * BK];
  const int t = threadIdx.x, wid = t >> 6, lane = t & 63;
  const int MT = (M + 127) >> 7;
  const int mt = blockIdx.x % MT, nt = blockIdx.x / MT;
  const int m0 = mt << 7, n0 = nt << 7;
  const int srow = t >> 3, sc = t & 7;

  const u16* gA[4]; const u16* gB[4]; int ldo[4];
#pragma unroll
  for (int i = 0; i < 4; ++i) {
    int rowi = srow + 32 * i;
    int ar = m0 + rowi; if (ar > M - 1) ar = M - 1;      // tail clamp
    int cp = (sc ^ (rowi & 7)) * 8;                      // pre-swizzled chunk
    gA[i] = A + (size_t)ar * K + cp;
    gB[i] = Bw + (size_t)(n0 + rowi) * K + cp;
    ldo[i] = t * 8 + i * 2048;                           // linear LDS dest
  }

  const int xr = lane & 7, g0 = lane >> 4;
  int aOff[4], bOff[4];
#pragma unroll
  for (int i = 0; i < 4; ++i) {
    aOff[i] = (((wid >> 1) << 6) + i * 16 + (lane & 15)) * BK + ((g0 ^ xr) << 3);
    bOff[i] = (((wid & 1) << 6) + i * 16 + (lane & 15)) * BK + ((g0 ^ xr) << 3);
  }

  f32x4 acc[4][4] = {};
  const int nk = K / BK;   // 8 or 16 (even)

  auto STAGE = [&](u16* dA, u16* dB, int ks) {
#pragma unroll
    for (int i = 0; i < 4; ++i) {
      gload16(gA[i] + ks * BK, dA + ldo[i]);
      gload16(gB[i] + ks * BK, dB + ldo[i]);
    }
  };
  auto COMPUTE = [&](const u16* lAc, const u16* lBc) {
#pragma unroll
    for (int kk = 0; kk < 2; ++kk) {
      bf16x8 af[4], bfr[4];
#pragma unroll
      for (int i = 0; i < 4; ++i) {
        af[i]  = *(const bf16x8*)(lAc + (aOff[i] ^ (kk << 5)));
        bfr[i] = *(const bf16x8*)(lBc + (bOff[i] ^ (kk << 5)));
      }
#pragma unroll
      for (int mi = 0; mi < 4; ++mi)
#pragma unroll
        for (int ni = 0; ni < 4; ++ni)
          acc[mi][ni] = __builtin_amdgcn_mfma_f32_16x16x32_bf16(af[mi], bfr[ni], acc[mi][ni], 0, 0, 0);
    }
  };

  STAGE(lA0, lB0, 0);
  __syncthreads();
#pragma unroll 1
  for (int ks = 0; ks < nk; ks += 2) {
    STAGE(lA1, lB1, ks + 1);
    COMPUTE(lA0, lB0);
    __syncthreads();
    if (ks + 2 < nk) STAGE(lA0, lB0, ks + 2);
    COMPUTE(lA1, lB1);
    __syncthreads();
  }

  const int rb = m0 + ((wid >> 1) << 6) + ((lane >> 4) << 2);
  const int cb = n0 + ((wid & 1) << 6) + (lane & 15);
  if (EP == 0) {
    float* O = (float*)Out;
#pragma unroll
    for (int mi = 0; mi < 4; ++mi)
#pragma unroll
      for (int ni = 0; ni < 4; ++ni) {
        int cc = cb + ni * 16;
#pragma unroll
        for (int r = 0; r < 4; ++r) {
          int rr = rb + mi * 16 + r;
          if (rr < M) O[(size_t)rr * N + cc] = acc[mi][ni][r];
        }
      }
  } else {
    u16* O = (u16*)Out;
    float bv[4];
#pragma unroll
    for (int ni = 0; ni < 4; ++ni) bv[ni] = bias[cb + ni * 16];
#pragma unroll
    for (int mi = 0; mi < 4; ++mi)
#pragma unroll
      for (int ni = 0; ni < 4; ++ni) {
        int cc = cb + ni * 16;
#pragma unroll
        for (int r = 0; r < 4; ++r) {
          int rr = rb + mi * 16 + r;
          float v = fmaxf(acc[mi][ni][r] + bv[ni], 0.0f);
          if (rr < M) O[(size_t)rr * N + cc] = f2bf(v);
        }
      }
  }
}

// ---------------- set LN: set_out = LN(set_feat + (u1 + cnt*b_vc)/9) ----------------
__global__ __launch_bounds__(256) void set_ln_k(const float* __restrict__ u1,
                                                const float* __restrict__ set_feat,
                                                const int* __restrict__ offs,
                                                const float* __restrict__ b_vc,
                                                const float* __restrict__ gam,
                                                const float* __restrict__ bet,
                                                float* __restrict__ set_out,
                                                u16* __restrict__ set_out_bf) {
  int row = blockIdx.x * 4 + (threadIdx.x >> 6);
  if (row >= MS) return;
  int lane = threadIdx.x & 63;
  int s = row % NS;
  float c9 = (float)(offs[s + 1] - offs[s]) * (1.0f / 9.0f);
  size_t base = (size_t)row * ND + lane * 8;
  f32x4 u0 = *(const f32x4*)(u1 + base),       u1b = *(const f32x4*)(u1 + base + 4);
  f32x4 s0 = *(const f32x4*)(set_feat + base), s1  = *(const f32x4*)(set_feat + base + 4);
  f32x4 b0 = *(const f32x4*)(b_vc + lane * 8), b1  = *(const f32x4*)(b_vc + lane * 8 + 4);
  f32x4 x0 = s0 + u0 * (1.0f / 9.0f) + b0 * c9;
  f32x4 x1 = s1 + u1b * (1.0f / 9.0f) + b1 * c9;
  float sm = 0.f, sq = 0.f;
#pragma unroll
  for (int i = 0; i < 4; ++i) { sm += x0[i] + x1[i]; sq += x0[i] * x0[i] + x1[i] * x1[i]; }
#pragma unroll
  for (int m = 32; m; m >>= 1) { sm += __shfl_xor(sm, m); sq += __shfl_xor(sq, m); }
  float mu = sm * (1.0f / ND);
  float rs = rsqrtf(sq * (1.0f / ND) - mu * mu + 1e-5f);
  f32x4 g0 = *(const f32x4*)(gam + lane * 8), g1 = *(const f32x4*)(gam + lane * 8 + 4);
  f32x4 e0 = *(const f32x4*)(bet + lane * 8), e1 = *(const f32x4*)(bet + lane * 8 + 4);
  f32x4 y0, y1; u16x8 ob;
#pragma unroll
  for (int i = 0; i < 4; ++i) {
    y0[i] = (x0[i] - mu) * rs * g0[i] + e0[i];
    y1[i] = (x1[i] - mu) * rs * g1[i] + e1[i];
    ob[i] = f2bf(y0[i]); ob[i + 4] = f2bf(y1[i]);
  }
  *(f32x4*)(set_out + base) = y0;
  *(f32x4*)(set_out + base + 4) = y1;
  *(u16x8*)(set_out_bf + base) = ob;
}

// ---------------- cand LN: cand_h = LN(cand_feat + mean3(proj) + b_vs) ----------------
__global__ __launch_bounds__(256) void cand_ln_k(const float* __restrict__ cand_feat,
                                                 const float* __restrict__ proj,
                                                 const int* __restrict__ cidx,
                                                 const float* __restrict__ b_vs,
                                                 const float* __restrict__ gam,
                                                 const float* __restrict__ bet,
                                                 u16* __restrict__ cand_h) {
  int row = blockIdx.x * 4 + (threadIdx.x >> 6);
  if (row >= MC) return;
  int lane = threadIdx.x & 63;
  int b = row / NC, c = row - b * NC;
  int i0 = cidx[c * 3], i1 = cidx[c * 3 + 1], i2 = cidx[c * 3 + 2];
  const float* pb = proj + (size_t)b * NS * ND + lane * 8;
  f32x4 p00 = *(const f32x4*)(pb + (size_t)i0 * ND), p01 = *(const f32x4*)(pb + (size_t)i0 * ND + 4);
  f32x4 p10 = *(const f32x4*)(pb + (size_t)i1 * ND), p11 = *(const f32x4*)(pb + (size_t)i1 * ND + 4);
  f32x4 p20 = *(const f32x4*)(pb + (size_t)i2 * ND), p21 = *(const f32x4*)(pb + (size_t)i2 * ND + 4);
  size_t base = (size_t)row * ND + lane * 8;
  f32x4 c0 = *(const f32x4*)(cand_feat + base), c1 = *(const f32x4*)(cand_feat + base + 4);
  f32x4 v0 = *(const f32x4*)(b_vs + lane * 8),  v1 = *(const f32x4*)(b_vs + lane * 8 + 4);
  const float third = 1.0f / 3.0f;
  f32x4 x0 = c0 + (p00 + p10 + p20) * third + v0;
  f32x4 x1 = c1 + (p01 + p11 + p21) * third + v1;
  float sm = 0.f, sq = 0.f;
#pragma unroll
  for (int i = 0; i < 4; ++i) { sm += x0[i] + x1[i]; sq += x0[i] * x0[i] + x1[i] * x1[i]; }
#pragma unroll
  for (int m = 32; m; m >>= 1) { sm += __shfl_xor(sm, m); sq += __shfl_xor(sq, m); }
  float mu = sm * (1.0f / ND);
  float rs = rsqrtf(sq * (1.0f / ND) - mu * mu + 1e-5f);
  f32x4 g0 = *(const f32x4*)(gam + lane * 8), g1 = *(const f32x4*)(gam + lane * 8 + 4);
  f32x4 e0 = *(const f32x4*)(bet + lane * 8), e1 = *(const f32x4*)(bet + lane * 8 + 4);
  u16x8 ob;
#pragma unroll
  for (int i = 0; i < 4; ++i) {
    ob[i]     = f2bf((x0[i] - mu) * rs * g0[i] + e0[i]);
    ob[i + 4] = f2bf((x1[i] - mu) * rs * g1[i] + e1[i]);
  }
  *(u16x8*)(cand_h + base) = ob;
}

// ======= FF2: GEMM (K=1024) + bias + residual + LayerNorm, in-place over h1 =======
// BM=64 x BN=512 (full row -> LN fusable), BK=64, 8 waves, dbuf 148KB LDS,
// coalesced+swizzled staging, STAGE||COMPUTE pipeline. M % 64 == 0.
__global__ __launch_bounds__(512, 2) void gemm_ff2_ln_k(const u16* __restrict__ A,   // h1: M x 1024
                                                        const u16* __restrict__ Bw,  // W2: 512 x 1024
                                                        const u16* __restrict__ resid, // cand_h: M x 512
                                                        const float* __restrict__ bias,
                                                        const float* __restrict__ gam,
                                                        const float* __restrict__ bet,
                                                        float* __restrict__ Out,     // M x 512 f32
                                                        int M) {
  constexpr int BK = 64, K = 1024, BM = 64, BN = 512;
  __shared__ u16 lA0[BM * BK], lA1[BM * BK];   // 8 KB each
  __shared__ u16 lB0[BN * BK], lB1[BN * BK];   // 64 KB each
  __shared__ float red[2][BM][8];              // 4 KB
  const int t = threadIdx.x, wid = t >> 6, lane = t & 63;
  const int m0 = blockIdx.x * BM;
  const int srow = t >> 3, sc = t & 7;          // srow 0..63
  const int cp = (sc ^ (srow & 7)) * 8;

  const u16* gA = A + (size_t)(m0 + srow) * K + cp;
  const u16* gB[8];
#pragma unroll
  for (int i = 0; i < 8; ++i) gB[i] = Bw + (size_t)(srow + 64 * i) * K + cp;

  const int xr = lane & 7, g0 = lane >> 4;
  int aOff[4], bOff[4];
#pragma unroll
  for (int i = 0; i < 4; ++i) {
    aOff[i] = (i * 16 + (lane & 15)) * BK + ((g0 ^ xr) << 3);
    bOff[i] = ((wid << 6) + i * 16 + (lane & 15)) * BK + ((g0 ^ xr) << 3);
  }

  f32x4 acc[4][4] = {};
  constexpr int nk = K / BK;   // 16

  auto STAGE = [&](u16* dA, u16* dB, int ks) {
    gload16(gA + ks * BK, dA + t * 8);
#pragma unroll
    for (int i = 0; i < 8; ++i) gload16(gB[i] + ks * BK, dB + i * 4096 + t * 8);
  };
  auto COMPUTE = [&](const u16* lAc, const u16* lBc) {
#pragma unroll
    for (int kk = 0; kk < 2; ++kk) {
      bf16x8 af[4], bfr[4];
#pragma unroll
      for (int i = 0; i < 4; ++i) {
        af[i]  = *(const bf16x8*)(lAc + (aOff[i] ^ (kk << 5)));
        bfr[i] = *(const bf16x8*)(lBc + (bOff[i] ^ (kk << 5)));
      }
#pragma unroll
      for (int mi = 0; mi < 4; ++mi)
#pragma unroll
        for (int ni = 0; ni < 4; ++ni)
          acc[mi][ni] = __builtin_amdgcn_mfma_f32_16x16x32_bf16(af[mi], bfr[ni], acc[mi][ni], 0, 0, 0);
    }
  };

  STAGE(lA0, lB0, 0);
  __syncthreads();
#pragma unroll 1
  for (int ks = 0; ks < nk; ks += 2) {
    STAGE(lA1, lB1, ks + 1);
    COMPUTE(lA0, lB0);
    __syncthreads();
    if (ks + 2 < nk) STAGE(lA0, lB0, ks + 2);
    COMPUTE(lA1, lB1);
    __syncthreads();
  }

  const int g = lane >> 4, li = lane & 15;
  float bv[4], gv[4], ev[4];
#pragma unroll
  for (int ni = 0; ni < 4; ++ni) {
    int col = (wid << 6) + ni * 16 + li;
    bv[ni] = bias[col]; gv[ni] = gam[col]; ev[ni] = bet[col];
  }
#pragma unroll
  for (int mi = 0; mi < 4; ++mi)
#pragma unroll
    for (int r = 0; r < 4; ++r) {
      int rl = mi * 16 + g * 4 + r;
      size_t rg = (size_t)(m0 + rl);
      float s = 0.f, q = 0.f;
#pragma unroll
      for (int ni = 0; ni < 4; ++ni) {
        int col = (wid << 6) + ni * 16 + li;
        float v = acc[mi][ni][r] + bv[ni] + bf2f(resid[rg * 512 + col]);
        acc[mi][ni][r] = v;
        s += v; q += v * v;
      }
#pragma unroll
      for (int m = 8; m; m >>= 1) { s += __shfl_xor(s, m); q += __shfl_xor(q, m); }
      if (li == 0) { red[0][rl][wid] = s; red[1][rl][wid] = q; }
    }
  __syncthreads();
#pragma unroll
  for (int mi = 0; mi < 4; ++mi)
#pragma unroll
    for (int r = 0; r < 4; ++r) {
      int rl = mi * 16 + g * 4 + r;
      float s = 0.f, q = 0.f;
#pragma unroll
      for (int w = 0; w < 8; ++w) { s += red[0][rl][w]; q += red[1][rl][w]; }
      float mu = s * (1.0f / 512.0f);
      float rs = rsqrtf(q * (1.0f / 512.0f) - mu * mu + 1e-5f);
      size_t rg = (size_t)(m0 + rl);
#pragma unroll
      for (int ni = 0; ni < 4; ++ni) {
        int col = (wid << 6) + ni * 16 + li;
        Out[rg * 512 + col] = (acc[mi][ni][r] - mu) * rs * gv[ni] + ev[ni];
      }
    }
}

// ---------------- launcher ----------------
extern "C" void kernel_launch(void* const* d_in, const int* in_sizes, int n_in,
                              void* d_out, int out_size, void* d_ws, size_t ws_size,
                              hipStream_t stream) {
  const float* cand_feat = (const float*)d_in[0];
  const float* set_feat  = (const float*)d_in[1];
  const float* W_vc  = (const float*)d_in[2];
  const float* b_vc  = (const float*)d_in[3];
  const float* W_vs  = (const float*)d_in[4];
  const float* b_vs  = (const float*)d_in[5];
  const float* ff_W1 = (const float*)d_in[6];
  const float* ff_b1 = (const float*)d_in[7];
  const float* ff_W2 = (const float*)d_in[8];
  const float* ff_b2 = (const float*)d_in[9];
  const float* g_set  = (const float*)d_in[10];
  const float* be_set = (const float*)d_in[11];
  const float* g_cand = (const float*)d_in[12];
  const float* be_cand= (const float*)d_in[13];
  const float* g_ff   = (const float*)d_in[14];
  const float* be_ff  = (const float*)d_in[15];
  const int*   cidx   = (const int*)d_in[16];
  (void)in_sizes; (void)n_in; (void)out_size; (void)ws_size;

  // workspace layout (~66 MiB)
  char* ws = (char*)d_ws;
  u16* w_vc_b = (u16*)(ws + 0);
  u16* w_vs_b = (u16*)(ws + (512 << 10));
  u16* w1_b   = (u16*)(ws + (1 << 20));
  u16* w2_b   = (u16*)(ws + (2 << 20));
  int* offs   = (int*)(ws + (3 << 20));
  int* list   = (int*)(ws + (3 << 20) + 4096);
  u16* setb   = (u16*)(ws + (4 << 20));        // 15.9 MB  set_out bf16
  u16* candh  = (u16*)(ws + (20 << 20));       // 45.6 MB  cand_h bf16

  // d_out region reuse (cand region = 95.55 MB, written last by FF2 kernel):
  float* out_cand = (float*)d_out;
  float* out_set  = out_cand + (size_t)MC * ND;
  u16*   agg  = (u16*)out_set;     // 15.9 MB, dead before set_out written
  float* u1   = out_cand;          // GEMM1 out, dead after set_ln
  float* proj = out_cand;          // GEMM2 out, dead after cand_ln
  u16*   h1   = (u16*)out_cand;    // FF1 out (46656 x 1024 bf16 = exactly the cand region)

  cast_bf16_k<<<(ND * ND / 4 + 255) / 256, 256, 0, stream>>>(W_vc, w_vc_b, ND * ND / 4);
  cast_bf16_k<<<(ND * ND / 4 + 255) / 256, 256, 0, stream>>>(W_vs, w_vs_b, ND * ND / 4);
  cast_bf16_k<<<(ND2 * ND / 4 + 255) / 256, 256, 0, stream>>>(ff_W1, w1_b, ND2 * ND / 4);
  cast_bf16_k<<<(ND * ND2 / 4 + 255) / 256, 256, 0, stream>>>(ff_W2, w2_b, ND * ND2 / 4);
  build_csr_k<<<1, 256, 0, stream>>>(cidx, offs, list);
  agg_k<<<(MS + 3) / 4, 256, 0, stream>>>(cand_feat, offs, list, agg);
  gemm_v3_k<0><<<122 * 4, 256, 0, stream>>>(agg, w_vc_b, u1, nullptr, MS, ND, ND);
  set_ln_k<<<(MS + 3) / 4, 256, 0, stream>>>(u1, set_feat, offs, b_vc, g_set, be_set, out_set, setb);
  gemm_v3_k<0><<<122 * 4, 256, 0, stream>>>(setb, w_vs_b, proj, nullptr, MS, ND, ND);
  cand_ln_k<<<(MC + 3) / 4, 256, 0, stream>>>(cand_feat, proj, cidx, b_vs, g_cand, be_cand, candh);
  gemm_v3_k<1><<<365 * 8, 256, 0, stream>>>(candh, w1_b, h1, ff_b1, MC, ND2, ND);
  gemm_ff2_ln_k<<<729, 512, 0, stream>>>(h1, w2_b, candh, ff_b2, g_ff, be_ff, out_cand, MC);
}